// Round 2
// baseline (96.734 us; speedup 1.0000x reference)
//
#include <hip/hip_runtime.h>

// QuantumLayer: boson-sampling distribution + linear head.
//   x:[512,8] f32, thetas:[12] f32, W:[4368,10] f32, b:[10] f32 -> out:[512,10] f32
// Identities:
//   * Columns of U evolve independently under row-ops => evolve only cols 0..4.
//   * Glynn (16 terms, delta_0=+1) instead of Ryser (32 masks); per-term sign
//     folded into rs (sign^5 == sign); 2^-4 prefactor squared -> 1/256 in norm.
//   * Prefix factorization: s-tuples sharing (m0..m3) form contiguous runs in
//     s-order (m4 = m3..11). Per prefix, pref[k] = prod of 4 row-sums is
//     computed once (32 VGPRs), each s then costs 16 b64 loads + 64 FMA.
//     1365 prefixes enumerated m3-major => equal run lengths across adjacent
//     lanes (no divergence); 3-pass weight-balanced thread assignment.

#define MODES 12
#define NPH   5
#define KG    16        // 2^(NPH-1) Glynn terms
#define S_TOT 4368      // C(16,5)
#define TPB   512
#define NOUT  10
#define NPREF 1365      // C(15,4) distinct 4-prefixes

#define TWO_PI_F 6.28318530717958647692f
#define RS2      0.70710678118654752440f

__device__ __forceinline__ int binom_small(int n, int r) {
  // C(n,r): exact stepwise (partial products are C(n,i+1)); r compile-time
  int p = 1;
  for (int i = 0; i < r; ++i) p = p * (n - i) / (i + 1);
  return p;
}
__device__ __forceinline__ int binom4(int n) {  // C(n,4); 0 for n<4
  return (n >= 4) ? (n * (n - 1) * (n - 2) * (n - 3)) / 24 : 0;
}

#define BFLY(i, j)                                                 \
  { float ar = ur[i], ai = ui[i], br = ur[j], bi = ui[j];          \
    ur[i] = RS2 * (ar - bi); ui[i] = RS2 * (ai + br);              \
    ur[j] = RS2 * (br - ai); ui[j] = RS2 * (bi + ar); }

__global__ __launch_bounds__(TPB, 4) void qlayer_kernel(
    const float* __restrict__ x,      // [B,8]
    const float* __restrict__ th,     // [12]
    const float* __restrict__ W,      // [S_TOT,10]
    const float* __restrict__ bias,   // [10]
    float* __restrict__ out)          // [B,10]
{
  __shared__ float2 rs[KG][MODES];    // Glynn row-sums, sign pre-folded
  __shared__ float2 uc[MODES][NPH];   // Ucols staging
  __shared__ float2 sc[20];           // (sin,cos) per layer
  __shared__ float  wred[8][NOUT];    // per-wave partials

  const int b = blockIdx.x;
  const int t = threadIdx.x;

  // ---------- Phase A0: all 20 sincos in parallel ----------
  if (t < 20) {
    float phi = (t < 12) ? th[t] : x[b * 8 + (t - 12)] * TWO_PI_F;
    float s, c;
    sincosf(phi, &s, &c);
    sc[t] = make_float2(s, c);
  }
  __syncthreads();

  // ---------- Phase A: evolve columns 0..4 of U (threads 0..4) ----------
  if (t < NPH) {
    float ur[MODES], ui[MODES];
    #pragma unroll
    for (int m = 0; m < MODES; ++m) { ur[m] = 0.f; ui[m] = 0.f; }
    ur[t] = 1.f;
    #pragma unroll
    for (int k = 0; k < 20; ++k) {
      const int mode = k % MODES;     // compile-time (k unrolled)
      float sp = sc[k].x, cp = sc[k].y;
      float re = ur[mode] * cp - ui[mode] * sp;
      float im = ur[mode] * sp + ui[mode] * cp;
      ur[mode] = re; ui[mode] = im;
      if ((k & 1) == 0) {             // BS_EVEN
        BFLY(0, 1) BFLY(2, 3) BFLY(4, 5) BFLY(6, 7) BFLY(8, 9) BFLY(10, 11)
      } else {                        // BS_ODD
        BFLY(1, 2) BFLY(3, 4) BFLY(5, 6) BFLY(7, 8) BFLY(9, 10)
      }
    }
    #pragma unroll
    for (int m = 0; m < MODES; ++m) uc[m][t] = make_float2(ur[m], ui[m]);
  }
  __syncthreads();

  // ---------- Phase B: rs[k][m] = sign_k * sum_c delta_c(k) * Ucols[m][c] ----------
  if (t < KG * MODES) {
    const int k = t / MODES;
    const int m = t - k * MODES;
    float sre = uc[m][0].x, sim = uc[m][0].y;   // delta_0 = +1
    #pragma unroll
    for (int c = 1; c < NPH; ++c) {
      float d = ((k >> (c - 1)) & 1) ? -1.f : 1.f;
      sre = fmaf(d, uc[m][c].x, sre);
      sim = fmaf(d, uc[m][c].y, sim);
    }
    float sg = (__popc((unsigned)k) & 1) ? -1.f : 1.f;
    rs[k][m] = make_float2(sg * sre, sg * sim);
  }
  __syncthreads();

  // ---------- Phase C: prefix-factorized permanents ----------
  float po[NOUT];
  #pragma unroll
  for (int o = 0; o < NOUT; ++o) po[o] = 0.f;

  auto process_prefix = [&](int r) {
    // r (m3-major prefix rank) -> group v (= m3), j within group
    int v = 0;
    while (r >= binom4(v + 4)) ++v;
    int j = r - binom4(v + 3);

    // unrank3: j-th non-decreasing (m0<=m1<=m2<=v), lex
    int m0, m1, m2;
    {
      int val = 0;
      for (; val < v; ++val) { int c2 = binom_small(v - val + 2, 2); if (j < c2) break; j -= c2; }
      m0 = val;
      for (val = m0; val < v; ++val) { int c2 = v - val + 1; if (j < c2) break; j -= c2; }
      m1 = val;
      m2 = m1 + j;
    }

    // s_base = lex rank of (m0,m1,m2,v,v) in CWR(12,5)
    int sbase = 0;
    for (int val = 0;  val < m0; ++val) sbase += binom_small(15 - val, 4);
    for (int val = m0; val < m1; ++val) sbase += binom_small(14 - val, 3);
    for (int val = m1; val < m2; ++val) sbase += binom_small(13 - val, 2);
    for (int val = m2; val < v;  ++val) sbase += 12 - val;

    // prefix Glynn products (held in regs across the run)
    float prr[KG], pri[KG];
    #pragma unroll
    for (int k = 0; k < KG; ++k) {
      float2 a  = rs[k][m0];
      float2 b2 = rs[k][m1];
      float2 c2 = rs[k][m2];
      float2 d2 = rs[k][v];
      float t1r = a.x * b2.x - a.y * b2.y, t1i = a.x * b2.y + a.y * b2.x;
      float t2r = c2.x * d2.x - c2.y * d2.y, t2i = c2.x * d2.y + c2.y * d2.x;
      prr[k] = t1r * t2r - t1i * t2i;
      pri[k] = t1r * t2i + t1i * t2r;
    }

    // norm: pm = prod of run-factorials of the 4-prefix; last-run count = run
    int run = 1, pm = 1;
    run = (m1 == m0) ? run + 1 : 1; pm *= run;
    run = (m2 == m1) ? run + 1 : 1; pm *= run;
    run = (v  == m2) ? run + 1 : 1; pm *= run;
    float inv_pm    = 1.0f / (256.0f * (float)pm);   // w > v
    float inv_first = inv_pm / (float)(run + 1);     // w == v extends run

    const float* wr = W + (size_t)sbase * NOUT;
    float invn = inv_first;
    for (int w = v; w < MODES; ++w) {
      float pr = 0.f, pi = 0.f;
      #pragma unroll
      for (int k = 0; k < KG; ++k) {
        float2 e = rs[k][w];
        pr = fmaf(prr[k], e.x, fmaf(-pri[k], e.y, pr));
        pi = fmaf(prr[k], e.y, fmaf(pri[k], e.x, pi));
      }
      float prob = (pr * pr + pi * pi) * invn;
      invn = inv_pm;
      #pragma unroll
      for (int o = 0; o < NOUT; ++o) po[o] = fmaf(prob, wr[o], po[o]);
      wr += NOUT;
    }
  };

  // weight-balanced coverage of ranks 0..1364:
  //   pass0: t (0..511), pass1: 1023-t (512..1023), pass2: 853+t (1024..1364)
  process_prefix(t);
  process_prefix(1023 - t);
  if (t >= 171) process_prefix(853 + t);

  // ---------- Phase D: block reduction ----------
  #pragma unroll
  for (int o = 0; o < NOUT; ++o) {
    float v = po[o];
    #pragma unroll
    for (int off = 32; off > 0; off >>= 1) v += __shfl_down(v, off, 64);
    po[o] = v;
  }
  const int lane = t & 63, wave = t >> 6;
  if (lane == 0) {
    #pragma unroll
    for (int o = 0; o < NOUT; ++o) wred[wave][o] = po[o];
  }
  __syncthreads();
  if (t < NOUT) {
    float acc = bias[t];
    #pragma unroll
    for (int w2 = 0; w2 < 8; ++w2) acc += wred[w2][t];
    out[b * NOUT + t] = acc;
  }
}

extern "C" void kernel_launch(void* const* d_in, const int* in_sizes, int n_in,
                              void* d_out, int out_size, void* d_ws, size_t ws_size,
                              hipStream_t stream) {
  (void)n_in; (void)out_size; (void)d_ws; (void)ws_size;
  const float* x    = (const float*)d_in[0];
  const float* th   = (const float*)d_in[1];
  const float* W    = (const float*)d_in[2];
  const float* bias = (const float*)d_in[3];
  float* out        = (float*)d_out;
  const int B = in_sizes[0] / 8;   // 512
  qlayer_kernel<<<B, TPB, 0, stream>>>(x, th, W, bias, out);
}

// Round 3
// 34.825 us; speedup vs baseline: 2.7777x; 2.7777x over previous
//
#include <hip/hip_runtime.h>

// QuantumLayer: boson-sampling distribution + linear head.
//   x:[512,8] f32, thetas:[12] f32, W:[4368,10] f32, b:[10] f32 -> out:[512,10] f32
// Identities:
//   * Columns of U evolve independently under row-ops => evolve only cols 0..4.
//   * Glynn (16 terms, delta_0=+1) instead of Ryser (32 masks); per-term sign
//     folded into rs (sign^5 == sign); 2^-4 prefactor squared -> 1/256 in norm.
//   * Prefix factorization: s-tuples sharing (m0..m3) are contiguous runs
//     (m4 = m3..11). Per prefix the 16 Glynn 4-row products are computed once
//     and held in 8 NAMED float4 regs (pf0..pf7, macro-expanded — no runtime
//     indexing => cannot be demoted to scratch; R2's 25MB/dispatch spill was
//     exactly this array in localMem).
//   * rs packed as float4 pairs (terms 2q,2q+1) => b128 LDS traffic.

#define MODES 12
#define NPH   5
#define KG    16
#define QG    8         // KG/2 packed pairs
#define S_TOT 4368
#define TPB   512
#define NOUT  10

#define TWO_PI_F 6.28318530717958647692f
#define RS2      0.70710678118654752440f

__device__ __forceinline__ int binom_small(int n, int r) {
  int p = 1;
  for (int i = 0; i < r; ++i) p = p * (n - i) / (i + 1);  // exact: partials are C(n,i+1)
  return p;
}
__device__ __forceinline__ int binom4(int n) {  // C(n,4); 0 for n<4
  return (n >= 4) ? (n * (n - 1) * (n - 2) * (n - 3)) / 24 : 0;
}

#define BFLY(i, j)                                                 \
  { float ar = ur[i], ai = ui[i], br = ur[j], bi = ui[j];          \
    ur[i] = RS2 * (ar - bi); ui[i] = RS2 * (ai + br);              \
    ur[j] = RS2 * (br - ai); ui[j] = RS2 * (bi + ar); }

// prefix product for packed pair q: pf_q = (rs_k0[m0]*rs_k0[m1]*rs_k0[m2]*rs_k0[v],
//                                           same for k1) as (re0,im0,re1,im1)
#define PREF(q)                                                              \
  { float4 a = rsp[q][m0], b2 = rsp[q][m1], c2 = rsp[q][m2], d2 = rsp[q][v]; \
    float t1r = a.x*b2.x - a.y*b2.y, t1i = a.x*b2.y + a.y*b2.x;              \
    float t2r = c2.x*d2.x - c2.y*d2.y, t2i = c2.x*d2.y + c2.y*d2.x;          \
    float u1r = a.z*b2.z - a.w*b2.w, u1i = a.z*b2.w + a.w*b2.z;              \
    float u2r = c2.z*d2.z - c2.w*d2.w, u2i = c2.z*d2.w + c2.w*d2.z;          \
    pf##q = make_float4(t1r*t2r - t1i*t2i, t1r*t2i + t1i*t2r,                \
                        u1r*u2r - u1i*u2i, u1r*u2i + u1i*u2r); }

// accumulate pair q's contribution of row w into (pr,pi)
#define WSTEP(q)                                                    \
  { float4 e = rsp[q][w];                                           \
    pr = fmaf(pf##q.x, e.x, pr); pr = fmaf(-pf##q.y, e.y, pr);      \
    pi = fmaf(pf##q.x, e.y, pi); pi = fmaf(pf##q.y, e.x, pi);       \
    pr = fmaf(pf##q.z, e.z, pr); pr = fmaf(-pf##q.w, e.w, pr);      \
    pi = fmaf(pf##q.z, e.w, pi); pi = fmaf(pf##q.w, e.z, pi); }

__global__ __launch_bounds__(TPB, 2) void qlayer_kernel(
    const float* __restrict__ x,      // [B,8]
    const float* __restrict__ th,     // [12]
    const float* __restrict__ W,      // [S_TOT,10]
    const float* __restrict__ bias,   // [10]
    float* __restrict__ out)          // [B,10]
{
  __shared__ float4 rsp[QG][MODES];   // packed Glynn row-sums, sign pre-folded
  __shared__ float2 uc[MODES][NPH];   // Ucols staging
  __shared__ float2 sc[20];           // (sin,cos) per layer
  __shared__ float  wred[8][NOUT];    // per-wave partials

  const int b = blockIdx.x;
  const int t = threadIdx.x;

  // ---------- Phase A0: all 20 sincos in parallel ----------
  if (t < 20) {
    float phi = (t < 12) ? th[t] : x[b * 8 + (t - 12)] * TWO_PI_F;
    float s, c;
    sincosf(phi, &s, &c);
    sc[t] = make_float2(s, c);
  }
  __syncthreads();

  // ---------- Phase A: evolve columns 0..4 of U (threads 0..4) ----------
  if (t < NPH) {
    float ur[MODES], ui[MODES];
    #pragma unroll
    for (int m = 0; m < MODES; ++m) { ur[m] = 0.f; ui[m] = 0.f; }
    ur[t] = 1.f;
    #pragma unroll
    for (int k = 0; k < 20; ++k) {
      const int mode = k % MODES;     // compile-time (k unrolled)
      float sp = sc[k].x, cp = sc[k].y;
      float re = ur[mode] * cp - ui[mode] * sp;
      float im = ur[mode] * sp + ui[mode] * cp;
      ur[mode] = re; ui[mode] = im;
      if ((k & 1) == 0) {             // BS_EVEN
        BFLY(0, 1) BFLY(2, 3) BFLY(4, 5) BFLY(6, 7) BFLY(8, 9) BFLY(10, 11)
      } else {                        // BS_ODD
        BFLY(1, 2) BFLY(3, 4) BFLY(5, 6) BFLY(7, 8) BFLY(9, 10)
      }
    }
    #pragma unroll
    for (int m = 0; m < MODES; ++m) uc[m][t] = make_float2(ur[m], ui[m]);
  }
  __syncthreads();

  // ---------- Phase B: packed row-sums rsp[q][m] for terms k=2q, 2q+1 ----------
  if (t < QG * MODES) {
    const int q = t / MODES;
    const int m = t - q * MODES;
    const int k0 = 2 * q, k1 = 2 * q + 1;
    float r0 = uc[m][0].x, i0 = uc[m][0].y;   // delta_0 = +1
    float r1 = r0, i1 = i0;
    #pragma unroll
    for (int c = 1; c < NPH; ++c) {
      float ux = uc[m][c].x, uy = uc[m][c].y;
      float d0 = ((k0 >> (c - 1)) & 1) ? -1.f : 1.f;
      float d1 = ((k1 >> (c - 1)) & 1) ? -1.f : 1.f;
      r0 = fmaf(d0, ux, r0); i0 = fmaf(d0, uy, i0);
      r1 = fmaf(d1, ux, r1); i1 = fmaf(d1, uy, i1);
    }
    float sg0 = (__popc((unsigned)k0) & 1) ? -1.f : 1.f;
    float sg1 = (__popc((unsigned)k1) & 1) ? -1.f : 1.f;
    rsp[q][m] = make_float4(sg0 * r0, sg0 * i0, sg1 * r1, sg1 * i1);
  }
  __syncthreads();

  // ---------- Phase C: prefix-factorized permanents ----------
  float po[NOUT];
  #pragma unroll
  for (int o = 0; o < NOUT; ++o) po[o] = 0.f;

  // weight-balanced coverage of prefix ranks 0..1364 (m3-major order):
  //   pass0: t, pass1: 1023-t, pass2: 853+t for t>=171
  for (int pass = 0; pass < 3; ++pass) {
    if (pass == 2 && t < 171) break;
    int r = (pass == 0) ? t : (pass == 1) ? (1023 - t) : (853 + t);

    // r -> group v (= m3), j within group
    int v = 0;
    while (r >= binom4(v + 4)) ++v;
    int j = r - binom4(v + 3);

    // unrank3: j-th non-decreasing (m0<=m1<=m2<=v), lex
    int m0, m1, m2;
    {
      int val = 0;
      for (; val < v; ++val) { int c2 = binom_small(v - val + 2, 2); if (j < c2) break; j -= c2; }
      m0 = val;
      for (val = m0; val < v; ++val) { int c2 = v - val + 1; if (j < c2) break; j -= c2; }
      m1 = val;
      m2 = m1 + j;
    }

    // s_base = lex rank of (m0,m1,m2,v,v) in CWR(12,5)
    int sbase = 0;
    for (int val = 0;  val < m0; ++val) sbase += binom_small(15 - val, 4);
    for (int val = m0; val < m1; ++val) sbase += binom_small(14 - val, 3);
    for (int val = m1; val < m2; ++val) sbase += binom_small(13 - val, 2);
    for (int val = m2; val < v;  ++val) sbase += 12 - val;

    // 16 prefix Glynn products in 8 NAMED float4 regs (no indexing!)
    float4 pf0, pf1, pf2, pf3, pf4, pf5, pf6, pf7;
    PREF(0) PREF(1) PREF(2) PREF(3) PREF(4) PREF(5) PREF(6) PREF(7)

    // norm: pm = prod of run-factorials of the 4-prefix
    int run = 1, pm = 1;
    run = (m1 == m0) ? run + 1 : 1; pm *= run;
    run = (m2 == m1) ? run + 1 : 1; pm *= run;
    run = (v  == m2) ? run + 1 : 1; pm *= run;
    float inv_pm    = 1.0f / (256.0f * (float)pm);   // w > v
    float inv_first = inv_pm / (float)(run + 1);     // w == v extends the run

    const float2* wr2 = (const float2*)(W + (size_t)sbase * NOUT);  // 40B rows, 8B-aligned
    float invn = inv_first;
    for (int w = v; w < MODES; ++w) {
      float pr = 0.f, pi = 0.f;
      WSTEP(0) WSTEP(1) WSTEP(2) WSTEP(3) WSTEP(4) WSTEP(5) WSTEP(6) WSTEP(7)
      float prob = (pr * pr + pi * pi) * invn;
      invn = inv_pm;
      float2 w01 = wr2[0], w23 = wr2[1], w45 = wr2[2], w67 = wr2[3], w89 = wr2[4];
      wr2 += 5;
      po[0] = fmaf(prob, w01.x, po[0]); po[1] = fmaf(prob, w01.y, po[1]);
      po[2] = fmaf(prob, w23.x, po[2]); po[3] = fmaf(prob, w23.y, po[3]);
      po[4] = fmaf(prob, w45.x, po[4]); po[5] = fmaf(prob, w45.y, po[5]);
      po[6] = fmaf(prob, w67.x, po[6]); po[7] = fmaf(prob, w67.y, po[7]);
      po[8] = fmaf(prob, w89.x, po[8]); po[9] = fmaf(prob, w89.y, po[9]);
    }
  }

  // ---------- Phase D: block reduction ----------
  #pragma unroll
  for (int o = 0; o < NOUT; ++o) {
    float v = po[o];
    #pragma unroll
    for (int off = 32; off > 0; off >>= 1) v += __shfl_down(v, off, 64);
    po[o] = v;
  }
  const int lane = t & 63, wave = t >> 6;
  if (lane == 0) {
    #pragma unroll
    for (int o = 0; o < NOUT; ++o) wred[wave][o] = po[o];
  }
  __syncthreads();
  if (t < NOUT) {
    float acc = bias[t];
    #pragma unroll
    for (int w2 = 0; w2 < 8; ++w2) acc += wred[w2][t];
    out[b * NOUT + t] = acc;
  }
}

extern "C" void kernel_launch(void* const* d_in, const int* in_sizes, int n_in,
                              void* d_out, int out_size, void* d_ws, size_t ws_size,
                              hipStream_t stream) {
  (void)n_in; (void)out_size; (void)d_ws; (void)ws_size;
  const float* x    = (const float*)d_in[0];
  const float* th   = (const float*)d_in[1];
  const float* W    = (const float*)d_in[2];
  const float* bias = (const float*)d_in[3];
  float* out        = (float*)d_out;
  const int B = in_sizes[0] / 8;   // 512
  qlayer_kernel<<<B, TPB, 0, stream>>>(x, th, W, bias, out);
}